// Round 1
// baseline (2078.061 us; speedup 1.0000x reference)
//
#include <hip/hip_runtime.h>
#include <math.h>

#define B_  4
#define C_  256
#define CK_ 32
#define N_  4096

#define TQ 32
#define TK 32
#define SV 36   // row stride (floats) for Qs/Vs/Ps: 144B, 16B-aligned, rotates banks by 4/row
#define SK 34   // row stride (floats) for Ks: 136B, 8B-aligned, rotates banks by 2/row

// ---------------- projection kernel: [Wb;Wc;Wd] @ x  ----------------
// grid (N_/64, 5, B_), block 256. Each block: 64 pixels x 64 out-channels.
__global__ __launch_bounds__(256) void proj_kernel(
    const float* __restrict__ x,
    const float* __restrict__ Wb, const float* __restrict__ bb,
    const float* __restrict__ Wc, const float* __restrict__ bc,
    const float* __restrict__ Wd, const float* __restrict__ bd,
    float* __restrict__ Q, float* __restrict__ K, float* __restrict__ V)
{
    const int t    = threadIdx.x;
    const int lane = t & 63;
    const int ty   = t >> 6;                 // 0..3 (uniform per wave)
    const int n0   = blockIdx.x * 64;
    const int g    = blockIdx.y;             // 0..4 -> channel group of 64
    const int b    = blockIdx.z;
    const int n    = n0 + lane;
    const int o0   = __builtin_amdgcn_readfirstlane(g * 64 + ty * 16);

    const float* wrow[16];
    float bias[16];
#pragma unroll
    for (int j = 0; j < 16; j++) {
        int o = o0 + j;
        if (o < 32)      { wrow[j] = Wb + o * C_;        bias[j] = bb[o]; }
        else if (o < 64) { wrow[j] = Wc + (o - 32) * C_; bias[j] = bc[o - 32]; }
        else             { wrow[j] = Wd + (o - 64) * C_; bias[j] = bd[o - 64]; }
    }

    const float* xp = x + (size_t)b * C_ * N_ + n;
    float acc[16];
#pragma unroll
    for (int j = 0; j < 16; j++) acc[j] = 0.f;

    for (int c = 0; c < C_; c += 4) {
        float x0 = xp[(size_t)(c + 0) * N_];
        float x1 = xp[(size_t)(c + 1) * N_];
        float x2 = xp[(size_t)(c + 2) * N_];
        float x3 = xp[(size_t)(c + 3) * N_];
#pragma unroll
        for (int j = 0; j < 16; j++) {
            const float4 w = *(const float4*)(wrow[j] + c);
            acc[j] += w.x * x0 + w.y * x1 + w.z * x2 + w.w * x3;
        }
    }

#pragma unroll
    for (int j = 0; j < 16; j++) {
        int o = o0 + j;
        float v = acc[j] + bias[j];
        if (o < 32)      Q[((size_t)b * N_ + n) * CK_ + o] = v;                 // (B,N,CK)
        else if (o < 64) K[((size_t)b * CK_ + (o - 32)) * N_ + n] = v;          // (B,CK,N)
        else             V[((size_t)b * C_  + (o - 64)) * N_ + n] = v;          // (B,C,N)
    }
}

// ---------------- flash attention + residual ----------------
// grid (N_/TQ, B_), block 256.
__global__ __launch_bounds__(256) void attn_kernel(
    const float* __restrict__ Q, const float* __restrict__ K, const float* __restrict__ V,
    const float* __restrict__ x, const float* __restrict__ gamma, float* __restrict__ out)
{
    __shared__ float Qs[TQ][SV];   // [q][k]
    __shared__ float Ks[TK][SK];   // [m][k]  (transposed keys)
    __shared__ float Vs[C_][SV];   // [ch][m]
    __shared__ float Ps[TQ][SV];   // [q][m]
    __shared__ float mx[TQ], ls[TQ], als[TQ];

    const int t  = threadIdx.x;
    const int b  = blockIdx.y;
    const int q0 = blockIdx.x * TQ;

    // load Q tile: TQ*CK = 1024 floats, 4 per thread
    {
        const float4 qv = *(const float4*)(Q + ((size_t)b * N_ + q0) * CK_ + t * 4);
        int qq = t >> 3, kk = (t & 7) * 4;
        *(float4*)&Qs[qq][kk] = qv;
    }
    if (t < TQ) { mx[t] = -1e30f; ls[t] = 0.f; }

    // PV mapping: thread owns q = qg*4+qi (qi 0..3), ch = cg + 32*j (j 0..7)
    const int qg = t >> 5;
    const int cg = t & 31;
    // score mapping: thread computes S[sq+8r][sm], r 0..3
    const int sm = t & 31;
    const int sq = t >> 5;

    float acc[4][8];
#pragma unroll
    for (int i = 0; i < 4; i++)
#pragma unroll
        for (int j = 0; j < 8; j++) acc[i][j] = 0.f;

    const float* Kb = K + (size_t)b * CK_ * N_;
    const float* Vb = V + (size_t)b * C_  * N_;

    __syncthreads();

    for (int m0 = 0; m0 < N_; m0 += TK) {
        // ---- stage K tile (transpose) ----
        {
            int k  = t >> 3;
            int mm = (t & 7) * 4;
            float4 kv = *(const float4*)(Kb + (size_t)k * N_ + m0 + mm);
            Ks[mm + 0][k] = kv.x; Ks[mm + 1][k] = kv.y;
            Ks[mm + 2][k] = kv.z; Ks[mm + 3][k] = kv.w;
        }
        // ---- stage V tile ----
        {
            int ch0 = t >> 3;
            int mm  = (t & 7) * 4;
#pragma unroll
            for (int i = 0; i < 8; i++) {
                int ch = ch0 + 32 * i;
                float4 vv = *(const float4*)(Vb + (size_t)ch * N_ + m0 + mm);
                *(float4*)&Vs[ch][mm] = vv;
            }
        }
        __syncthreads();

        // ---- scores: S = Q . K ----
        {
            float s[4] = {0.f, 0.f, 0.f, 0.f};
#pragma unroll
            for (int k2 = 0; k2 < CK_ / 2; k2++) {
                float2 kv = *(const float2*)&Ks[sm][2 * k2];
#pragma unroll
                for (int r = 0; r < 4; r++) {
                    float2 qv = *(const float2*)&Qs[sq + 8 * r][2 * k2];
                    s[r] += qv.x * kv.x + qv.y * kv.y;
                }
            }
#pragma unroll
            for (int r = 0; r < 4; r++) Ps[sq + 8 * r][sm] = s[r];
        }
        __syncthreads();

        // ---- online softmax update (one wave) ----
        if (t < TQ) {
            float mold = mx[t];
            float tmax = -1e30f;
#pragma unroll 4
            for (int m = 0; m < TK; m++) tmax = fmaxf(tmax, Ps[t][m]);
            float mnew = fmaxf(mold, tmax);
            float al   = __expf(mold - mnew);
            float ssum = 0.f;
#pragma unroll 4
            for (int m = 0; m < TK; m++) {
                float p = __expf(Ps[t][m] - mnew);
                Ps[t][m] = p;
                ssum += p;
            }
            mx[t]  = mnew;
            ls[t]  = ls[t] * al + ssum;
            als[t] = al;
        }
        __syncthreads();

        // ---- PV accumulate ----
        {
            float al0 = als[qg * 4 + 0], al1 = als[qg * 4 + 1];
            float al2 = als[qg * 4 + 2], al3 = als[qg * 4 + 3];
#pragma unroll
            for (int j = 0; j < 8; j++) {
                acc[0][j] *= al0; acc[1][j] *= al1;
                acc[2][j] *= al2; acc[3][j] *= al3;
            }
#pragma unroll
            for (int m4 = 0; m4 < TK / 4; m4++) {
                float4 p0 = *(const float4*)&Ps[qg * 4 + 0][m4 * 4];
                float4 p1 = *(const float4*)&Ps[qg * 4 + 1][m4 * 4];
                float4 p2 = *(const float4*)&Ps[qg * 4 + 2][m4 * 4];
                float4 p3 = *(const float4*)&Ps[qg * 4 + 3][m4 * 4];
#pragma unroll
                for (int j = 0; j < 8; j++) {
                    float4 vv = *(const float4*)&Vs[cg + 32 * j][m4 * 4];
                    acc[0][j] += p0.x * vv.x + p0.y * vv.y + p0.z * vv.z + p0.w * vv.w;
                    acc[1][j] += p1.x * vv.x + p1.y * vv.y + p1.z * vv.z + p1.w * vv.w;
                    acc[2][j] += p2.x * vv.x + p2.y * vv.y + p2.z * vv.z + p2.w * vv.w;
                    acc[3][j] += p3.x * vv.x + p3.y * vv.y + p3.z * vv.z + p3.w * vv.w;
                }
            }
        }
        __syncthreads();
    }

    // ---- epilogue: transpose through Vs for coalesced residual+store ----
#pragma unroll
    for (int i = 0; i < 4; i++)
#pragma unroll
        for (int j = 0; j < 8; j++)
            Vs[cg + 32 * j][qg * 4 + i] = acc[i][j];
    __syncthreads();

    const float g = gamma[0];
    {
        int ch0 = t >> 3;
        int mm  = (t & 7) * 4;
        float il0 = 1.f / ls[mm + 0], il1 = 1.f / ls[mm + 1];
        float il2 = 1.f / ls[mm + 2], il3 = 1.f / ls[mm + 3];
#pragma unroll
        for (int i = 0; i < 8; i++) {
            int ch = ch0 + 32 * i;
            float4 vv  = *(const float4*)&Vs[ch][mm];
            const float4 xin = *(const float4*)(x + ((size_t)b * C_ + ch) * N_ + q0 + mm);
            float4 o;
            o.x = g * vv.x * il0 + xin.x;
            o.y = g * vv.y * il1 + xin.y;
            o.z = g * vv.z * il2 + xin.z;
            o.w = g * vv.w * il3 + xin.w;
            *(float4*)(out + ((size_t)b * C_ + ch) * N_ + q0 + mm) = o;
        }
    }
}

extern "C" void kernel_launch(void* const* d_in, const int* in_sizes, int n_in,
                              void* d_out, int out_size, void* d_ws, size_t ws_size,
                              hipStream_t stream)
{
    const float* x  = (const float*)d_in[0];
    const float* Wb = (const float*)d_in[1];
    const float* bb = (const float*)d_in[2];
    const float* Wc = (const float*)d_in[3];
    const float* bc = (const float*)d_in[4];
    const float* Wd = (const float*)d_in[5];
    const float* bd = (const float*)d_in[6];
    const float* gm = (const float*)d_in[7];
    float* out = (float*)d_out;

    float* Qw = (float*)d_ws;                        // B*N*CK floats
    float* Kw = Qw + (size_t)B_ * N_ * CK_;          // B*CK*N floats
    float* Vw = Kw + (size_t)B_ * CK_ * N_;          // B*C*N floats

    proj_kernel<<<dim3(N_ / 64, 5, B_), 256, 0, stream>>>(x, Wb, bb, Wc, bc, Wd, bd, Qw, Kw, Vw);
    attn_kernel<<<dim3(N_ / TQ, B_), 256, 0, stream>>>(Qw, Kw, Vw, x, gm, out);
}

// Round 2
// 365.493 us; speedup vs baseline: 5.6856x; 5.6856x over previous
//
#include <hip/hip_runtime.h>
#include <math.h>

#define B_  4
#define C_  256
#define CK_ 32
#define N_  4096

typedef __attribute__((ext_vector_type(8))) short v8s;
typedef __attribute__((ext_vector_type(4))) float v4f;

__device__ inline unsigned short f2bf(float f) {
    unsigned u = __builtin_bit_cast(unsigned, f);
    unsigned r = (u + 0x7fffu + ((u >> 16) & 1u)) >> 16;
    return (unsigned short)r;
}

// ---------------- projection kernel: [Wb;Wc;Wd] @ x -> bf16 Q,K,V ----------------
// grid (N_/64, 5, B_), block 256. Each block: 64 pixels x 64 out-channels.
// Q: (B,N,32) bf16   K: (B,N,32) bf16 (keys transposed)   V: (B,C,N) bf16
__global__ __launch_bounds__(256) void proj_kernel(
    const float* __restrict__ x,
    const float* __restrict__ Wb, const float* __restrict__ bb,
    const float* __restrict__ Wc, const float* __restrict__ bc,
    const float* __restrict__ Wd, const float* __restrict__ bd,
    unsigned short* __restrict__ Q, unsigned short* __restrict__ K,
    unsigned short* __restrict__ V)
{
    const int t    = threadIdx.x;
    const int lane = t & 63;
    const int ty   = t >> 6;                 // 0..3 (uniform per wave)
    const int n0   = blockIdx.x * 64;
    const int g    = blockIdx.y;             // 0..4 -> channel group of 64
    const int b    = blockIdx.z;
    const int n    = n0 + lane;
    const int o0   = __builtin_amdgcn_readfirstlane(g * 64 + ty * 16);

    const float* wrow[16];
    float bias[16];
#pragma unroll
    for (int j = 0; j < 16; j++) {
        int o = o0 + j;
        if (o < 32)      { wrow[j] = Wb + o * C_;        bias[j] = bb[o]; }
        else if (o < 64) { wrow[j] = Wc + (o - 32) * C_; bias[j] = bc[o - 32]; }
        else             { wrow[j] = Wd + (o - 64) * C_; bias[j] = bd[o - 64]; }
    }

    const float* xp = x + (size_t)b * C_ * N_ + n;
    float acc[16];
#pragma unroll
    for (int j = 0; j < 16; j++) acc[j] = 0.f;

    for (int c = 0; c < C_; c += 4) {
        float x0 = xp[(size_t)(c + 0) * N_];
        float x1 = xp[(size_t)(c + 1) * N_];
        float x2 = xp[(size_t)(c + 2) * N_];
        float x3 = xp[(size_t)(c + 3) * N_];
#pragma unroll
        for (int j = 0; j < 16; j++) {
            const float4 w = *(const float4*)(wrow[j] + c);
            acc[j] += w.x * x0 + w.y * x1 + w.z * x2 + w.w * x3;
        }
    }

    unsigned short ub[16];
#pragma unroll
    for (int j = 0; j < 16; j++) ub[j] = f2bf(acc[j] + bias[j]);

    if (g == 0) {
        // Q part (o0 in {0,16}) or K part (o0 in {32,48}); 32B packed store per lane
        unsigned p[8];
#pragma unroll
        for (int i = 0; i < 8; i++)
            p[i] = (unsigned)ub[2 * i] | ((unsigned)ub[2 * i + 1] << 16);
        uint4 lo = make_uint4(p[0], p[1], p[2], p[3]);
        uint4 hi = make_uint4(p[4], p[5], p[6], p[7]);
        unsigned short* dst = (o0 < 32)
            ? (Q + ((size_t)b * N_ + n) * 32 + o0)
            : (K + ((size_t)b * N_ + n) * 32 + (o0 - 32));
        *(uint4*)(dst)     = lo;
        *(uint4*)(dst + 8) = hi;
    } else {
        int c0 = (g - 1) * 64 + ty * 16;
#pragma unroll
        for (int j = 0; j < 16; j++)
            V[((size_t)b * C_ + (c0 + j)) * N_ + n] = ub[j];
    }
}

// ---------------- MFMA flash attention + residual ----------------
// grid (N_/64, B_), block 512 (8 waves). Block: 64 queries, full C=256 out.
// Computes O^T[c][q] = sum_m V[c][m] * P[q][m] with online softmax over m.
__global__ __launch_bounds__(512) void attn_mfma(
    const unsigned short* __restrict__ Qg, const unsigned short* __restrict__ Kg,
    const unsigned short* __restrict__ Vg, const float* __restrict__ x,
    const float* __restrict__ gamma, float* __restrict__ out)
{
    __shared__ unsigned short KQ[64][40];   // [m][k] keys (also Q staging) bf16
    __shared__ unsigned short Vs[256][72];  // [c][m] bf16
    __shared__ float          Ss[64][68];   // [q][m] scores fp32
    __shared__ unsigned short Ps[64][72];   // [q][m] P bf16
    __shared__ float mrow[64], lrow[64], alr[64];

    const int t   = threadIdx.x;
    const int w   = t >> 6;      // wave 0..7
    const int l   = t & 63;
    const int l16 = l & 15;
    const int lg  = l >> 4;      // 0..3
    const int b   = blockIdx.y;
    const int q0  = blockIdx.x * 64;

    // ---- stage Q tile (rows q0..q0+63, 32 k) into KQ ----
    if (t < 256) {
        int m = t >> 2, ch = t & 3;
        uint4 v = *(const uint4*)(Qg + ((size_t)b * N_ + q0 + m) * 32 + ch * 8);
        *(uint4*)&KQ[m][ch * 8] = v;
    }
    if (t < 64) { mrow[t] = -3.0e38f; lrow[t] = 0.f; }
    __syncthreads();

    // S-phase assignment: wave w -> q-subtile (w>>1), m-subtiles {2(w&1), 2(w&1)+1}
    const int qsub_s = w >> 1;
    const int ms0    = (w & 1) * 2;
    // preload Q A-frag (constant across iterations): A[i=q][k], i=l16, k=8*lg+e
    const v8s aQ = *(const v8s*)&KQ[qsub_s * 16 + l16][lg * 8];

    // PV accumulators: wave owns c-subtiles {2w, 2w+1} x q-subtiles 0..3 (O^T tiles)
    v4f acc[2][4];
#pragma unroll
    for (int cs = 0; cs < 2; cs++)
#pragma unroll
        for (int qs = 0; qs < 4; qs++) {
            v4f z = {0.f, 0.f, 0.f, 0.f};
            acc[cs][qs] = z;
        }

    for (int m0 = 0; m0 < N_; m0 += 64) {
        __syncthreads();  // A: prev-iter PV / Q-frag reads done

        // ---- stage K tile ----
        if (t < 256) {
            int m = t >> 2, ch = t & 3;
            uint4 v = *(const uint4*)(Kg + ((size_t)b * N_ + m0 + m) * 32 + ch * 8);
            *(uint4*)&KQ[m][ch * 8] = v;
        }
        // ---- stage V tile: 256 c x 64 m bf16 ----
        {
            int c = t >> 1, h = t & 1;
            const unsigned short* src = Vg + ((size_t)b * C_ + c) * N_ + m0 + h * 32;
#pragma unroll
            for (int j = 0; j < 4; j++)
                *(uint4*)&Vs[c][h * 32 + j * 8] = *(const uint4*)(src + j * 8);
        }
        __syncthreads();  // B: staging done

        // ---- S = Q . K^T  (16x16x32 MFMA, 2 subtiles per wave) ----
#pragma unroll
        for (int mi = 0; mi < 2; mi++) {
            int ms = ms0 + mi;
            v8s bK = *(const v8s*)&KQ[ms * 16 + l16][lg * 8];
            v4f z = {0.f, 0.f, 0.f, 0.f};
            v4f s = __builtin_amdgcn_mfma_f32_16x16x32_bf16(aQ, bK, z, 0, 0, 0);
#pragma unroll
            for (int r = 0; r < 4; r++)
                Ss[qsub_s * 16 + lg * 4 + r][ms * 16 + l16] = s[r];
        }
        __syncthreads();  // C: scores written

        // ---- online softmax (512 threads: 8 per row) ----
        {
            int row = t >> 3, c0 = (t & 7) * 8;
            float4 s0 = *(const float4*)&Ss[row][c0];
            float4 s1 = *(const float4*)&Ss[row][c0 + 4];
            float tmax = fmaxf(fmaxf(fmaxf(s0.x, s0.y), fmaxf(s0.z, s0.w)),
                               fmaxf(fmaxf(s1.x, s1.y), fmaxf(s1.z, s1.w)));
            tmax = fmaxf(tmax, __shfl_xor(tmax, 1));
            tmax = fmaxf(tmax, __shfl_xor(tmax, 2));
            tmax = fmaxf(tmax, __shfl_xor(tmax, 4));
            float mold = mrow[row];
            float mnew = fmaxf(mold, tmax);
            float al   = __expf(mold - mnew);
            float p0 = __expf(s0.x - mnew), p1 = __expf(s0.y - mnew);
            float p2 = __expf(s0.z - mnew), p3 = __expf(s0.w - mnew);
            float p4 = __expf(s1.x - mnew), p5 = __expf(s1.y - mnew);
            float p6 = __expf(s1.z - mnew), p7 = __expf(s1.w - mnew);
            uint4 pk = make_uint4(
                (unsigned)f2bf(p0) | ((unsigned)f2bf(p1) << 16),
                (unsigned)f2bf(p2) | ((unsigned)f2bf(p3) << 16),
                (unsigned)f2bf(p4) | ((unsigned)f2bf(p5) << 16),
                (unsigned)f2bf(p6) | ((unsigned)f2bf(p7) << 16));
            *(uint4*)&Ps[row][c0] = pk;
            float ps = ((p0 + p1) + (p2 + p3)) + ((p4 + p5) + (p6 + p7));
            ps += __shfl_xor(ps, 1);
            ps += __shfl_xor(ps, 2);
            ps += __shfl_xor(ps, 4);
            if ((t & 7) == 0) {
                lrow[row] = lrow[row] * al + ps;
                mrow[row] = mnew;
                alr[row]  = al;
            }
        }
        __syncthreads();  // D: P + alphas ready

        // ---- PV: O^T[c][q] accumulate (16x16x32 MFMA) ----
        {
            float a0 = alr[l16], a1 = alr[16 + l16], a2 = alr[32 + l16], a3 = alr[48 + l16];
#pragma unroll
            for (int cs = 0; cs < 2; cs++) {
#pragma unroll
                for (int r = 0; r < 4; r++) {
                    acc[cs][0][r] *= a0; acc[cs][1][r] *= a1;
                    acc[cs][2][r] *= a2; acc[cs][3][r] *= a3;
                }
            }
#pragma unroll
            for (int kc = 0; kc < 2; kc++) {
                v8s bP[4];
#pragma unroll
                for (int qs = 0; qs < 4; qs++)
                    bP[qs] = *(const v8s*)&Ps[qs * 16 + l16][kc * 32 + lg * 8];
#pragma unroll
                for (int cs = 0; cs < 2; cs++) {
                    v8s aV = *(const v8s*)&Vs[(w * 2 + cs) * 16 + l16][kc * 32 + lg * 8];
#pragma unroll
                    for (int qs = 0; qs < 4; qs++)
                        acc[cs][qs] = __builtin_amdgcn_mfma_f32_16x16x32_bf16(
                            aV, bP[qs], acc[cs][qs], 0, 0, 0);
                }
            }
        }
    }

    // ---- epilogue: out[b][c][n] = gamma * O^T[c][n]/l[n] + x[b][c][n] ----
    const float gm = gamma[0];
#pragma unroll
    for (int qs = 0; qs < 4; qs++) {
        float il = 1.0f / lrow[qs * 16 + l16];
        int   n  = q0 + qs * 16 + l16;
#pragma unroll
        for (int cs = 0; cs < 2; cs++) {
#pragma unroll
            for (int r = 0; r < 4; r++) {
                int c = (w * 2 + cs) * 16 + lg * 4 + r;
                size_t idx = ((size_t)b * C_ + c) * N_ + n;
                out[idx] = gm * (acc[cs][qs][r] * il) + x[idx];
            }
        }
    }
}

extern "C" void kernel_launch(void* const* d_in, const int* in_sizes, int n_in,
                              void* d_out, int out_size, void* d_ws, size_t ws_size,
                              hipStream_t stream)
{
    const float* x  = (const float*)d_in[0];
    const float* Wb = (const float*)d_in[1];
    const float* bb = (const float*)d_in[2];
    const float* Wc = (const float*)d_in[3];
    const float* bc = (const float*)d_in[4];
    const float* Wd = (const float*)d_in[5];
    const float* bd = (const float*)d_in[6];
    const float* gm = (const float*)d_in[7];
    float* out = (float*)d_out;

    unsigned short* Qw = (unsigned short*)d_ws;            // B*N*32 bf16
    unsigned short* Kw = Qw + (size_t)B_ * N_ * 32;        // B*N*32 bf16
    unsigned short* Vw = Kw + (size_t)B_ * N_ * 32;        // B*C*N bf16

    proj_kernel<<<dim3(N_ / 64, 5, B_), 256, 0, stream>>>(x, Wb, bb, Wc, bc, Wd, bd,
                                                          Qw, Kw, Vw);
    attn_mfma<<<dim3(N_ / 64, B_), 512, 0, stream>>>(Qw, Kw, Vw, x, gm, out);
}

// Round 3
// 329.124 us; speedup vs baseline: 6.3139x; 1.1105x over previous
//
#include <hip/hip_runtime.h>
#include <math.h>

#define B_  4
#define C_  256
#define N_  4096

typedef __attribute__((ext_vector_type(8))) short v8s;
typedef __attribute__((ext_vector_type(4))) float v4f;

__device__ inline unsigned short f2bf(float f) {
    unsigned u = __builtin_bit_cast(unsigned, f);
    unsigned r = (u + 0x7fffu + ((u >> 16) & 1u)) >> 16;
    return (unsigned short)r;
}
__device__ inline unsigned pack2bf(float a, float b) {
    return (unsigned)f2bf(a) | ((unsigned)f2bf(b) << 16);
}

// ---------------- W convert: Wcat rows 0..255=Wd, 256..287=Wb, 288..319=Wc ----------------
__global__ __launch_bounds__(256) void wcvt_kernel(
    const float* __restrict__ Wb, const float* __restrict__ Wc,
    const float* __restrict__ Wd, unsigned short* __restrict__ Wcat)
{
    int i = (blockIdx.x * 256 + threadIdx.x) * 4;   // 81920 elems, grid 80
    int row = i >> 8, col = i & 255;
    const float* src;
    if (row < 256)      src = Wd + row * 256 + col;
    else if (row < 288) src = Wb + (row - 256) * 256 + col;
    else                src = Wc + (row - 288) * 256 + col;
    float4 v = *(const float4*)src;
    uint2 p;
    p.x = pack2bf(v.x, v.y);
    p.y = pack2bf(v.z, v.w);
    *(uint2*)(Wcat + i) = p;
}

// ---------------- MFMA projection: 320x256 @ x-tile(256x64) ----------------
// grid (N_/64, B_), block 512 (8 waves). Wave w: row-subtiles {2w,2w+1} (+16+w for w<4).
#define XS_STRIDE 264
__global__ __launch_bounds__(512) void proj_mfma(
    const float* __restrict__ x, const unsigned short* __restrict__ Wcat,
    const float* __restrict__ bb, const float* __restrict__ bc,
    const float* __restrict__ bd,
    unsigned short* __restrict__ Q, unsigned short* __restrict__ K,
    unsigned short* __restrict__ V)
{
    __shared__ unsigned short Xs[64][XS_STRIDE];   // [n][c] bf16
    const int t = threadIdx.x;
    const int w = t >> 6, l = t & 63, l16 = l & 15, lg = l >> 4;
    const int n0 = blockIdx.x * 64, b = blockIdx.y;

    // ---- stage x tile transposed to bf16: thread (n=t&63, cb=t>>6) ----
    {
        const int n = t & 63, cb = t >> 6;
        const float* xp = x + (size_t)b * C_ * N_ + n0 + n;
#pragma unroll
        for (int it = 0; it < 4; it++) {
            int c0 = it * 64 + cb * 8;
            unsigned pk[4];
#pragma unroll
            for (int j = 0; j < 4; j++) {
                float a  = xp[(size_t)(c0 + 2 * j) * N_];
                float bv = xp[(size_t)(c0 + 2 * j + 1) * N_];
                pk[j] = pack2bf(a, bv);
            }
            *(uint4*)&Xs[n][c0] = make_uint4(pk[0], pk[1], pk[2], pk[3]);
        }
    }
    __syncthreads();

    const int nsubs = (w < 4) ? 3 : 2;
    int sublist[3] = {2 * w, 2 * w + 1, 16 + w};

    for (int si = 0; si < nsubs; si++) {
        int sub = sublist[si];
        // A-frags: W rows sub*16..+16, all 8 k-steps
        v8s aw[8];
#pragma unroll
        for (int kk = 0; kk < 8; kk++)
            aw[kk] = *(const v8s*)(Wcat + (size_t)(sub * 16 + l16) * 256 + kk * 32 + lg * 8);

        if (sub < 16) {
            float bi[4];
#pragma unroll
            for (int r = 0; r < 4; r++) bi[r] = bd[sub * 16 + lg * 4 + r];
#pragma unroll
            for (int ns = 0; ns < 4; ns++) {
                v4f acc = {0.f, 0.f, 0.f, 0.f};
#pragma unroll
                for (int kk = 0; kk < 8; kk++) {
                    v8s bx = *(const v8s*)&Xs[ns * 16 + l16][kk * 32 + lg * 8];
                    acc = __builtin_amdgcn_mfma_f32_16x16x32_bf16(aw[kk], bx, acc, 0, 0, 0);
                }
                int n = n0 + ns * 16 + l16;
#pragma unroll
                for (int r = 0; r < 4; r++) {
                    int c = sub * 16 + lg * 4 + r;
                    V[((size_t)b * C_ + c) * N_ + n] = f2bf(acc[r] + bi[r]);
                }
            }
        } else {
            int qk = sub - 16;               // 0,1 -> Q ; 2,3 -> K
            bool isQ = (qk < 2);
            int o0l = (qk & 1) * 16;
            const float* bias = isQ ? bb : bc;
            unsigned short* dst = isQ ? Q : K;
            float bi[4];
#pragma unroll
            for (int r = 0; r < 4; r++) bi[r] = bias[o0l + lg * 4 + r];
#pragma unroll
            for (int ns = 0; ns < 4; ns++) {
                v4f acc = {0.f, 0.f, 0.f, 0.f};
#pragma unroll
                for (int kk = 0; kk < 8; kk++) {
                    v8s bx = *(const v8s*)&Xs[ns * 16 + l16][kk * 32 + lg * 8];
                    acc = __builtin_amdgcn_mfma_f32_16x16x32_bf16(aw[kk], bx, acc, 0, 0, 0);
                }
                int n = n0 + ns * 16 + l16;
                uint2 pk;
                pk.x = pack2bf(acc[0] + bi[0], acc[1] + bi[1]);
                pk.y = pack2bf(acc[2] + bi[2], acc[3] + bi[3]);
                *(uint2*)(dst + ((size_t)b * N_ + n) * 32 + o0l + lg * 4) = pk;
            }
        }
    }
}

// ---------------- MFMA flash attention, swapped S^T + in-reg softmax ----------------
// grid (N_/64, B_), block 512 (8 waves). wave w: qs = w&3 (16 q's), ws = w>>2 (m-half).
#define KS_STR 40
#define VS_STR 72
#define PT_STR 72
__global__ __launch_bounds__(512) void attn_mfma(
    const unsigned short* __restrict__ Qg, const unsigned short* __restrict__ Kg,
    const unsigned short* __restrict__ Vg, const float* __restrict__ x,
    const float* __restrict__ gamma, float* __restrict__ out)
{
    __shared__ unsigned short Ks[64][KS_STR];   // [m][k]
    __shared__ unsigned short Vs[256][VS_STR];  // [c][m]
    __shared__ unsigned short Pt[64][PT_STR];   // [q][m]
    __shared__ float mrow[64], lrow[64], alr[64];
    __shared__ float pmax2[2][64], psum2[2][64];

    const int t = threadIdx.x;
    const int w = t >> 6, l = t & 63, l16 = l & 15, lg = l >> 4;
    const int qs = w & 3, ws = w >> 2;
    const int b = blockIdx.y, q0 = blockIdx.x * 64;
    const int q = qs * 16 + l16;

    // Q B-frag, constant all kernel (direct from global)
    const v8s bQ = *(const v8s*)(Qg + ((size_t)b * N_ + q0 + q) * 32 + lg * 8);

    if (t < 64) { mrow[t] = -3.0e38f; lrow[t] = 0.f; }

    // T14 prefetch registers
    const int vc = t >> 1, vh = t & 1;
    const unsigned short* Vsrc = Vg + ((size_t)b * C_ + vc) * N_ + vh * 32;
    const int km = (t - 256) >> 2, kch = (t - 256) & 3;
    const unsigned short* Ksrc = Kg + ((size_t)b * N_ + km) * 32 + kch * 8;

    uint4 vr[4]; uint4 kr;
#pragma unroll
    for (int j = 0; j < 4; j++) vr[j] = *(const uint4*)(Vsrc + j * 8);
    if (t >= 256) kr = *(const uint4*)(Ksrc);

    v4f acc[2][4];
#pragma unroll
    for (int cs = 0; cs < 2; cs++)
#pragma unroll
        for (int qq = 0; qq < 4; qq++) {
            v4f z = {0.f, 0.f, 0.f, 0.f};
            acc[cs][qq] = z;
        }

#pragma unroll 1
    for (int it = 0; it < N_ / 64; it++) {
        __syncthreads();                         // B1: LDS free (prev PV done)
#pragma unroll
        for (int j = 0; j < 4; j++) *(uint4*)&Vs[vc][vh * 32 + j * 8] = vr[j];
        if (t >= 256) *(uint4*)&Ks[km][kch * 8] = kr;
        if (it + 1 < N_ / 64) {                  // issue next tile's loads
            int m1 = (it + 1) * 64;
#pragma unroll
            for (int j = 0; j < 4; j++) vr[j] = *(const uint4*)(Vsrc + m1 + j * 8);
            if (t >= 256) kr = *(const uint4*)(Ksrc + (size_t)m1 * 32);
        }
        __syncthreads();                         // B2: stage visible

        // ---- S^T = K . Q^T : D[i=m][j=q], 2 subtiles (m-half ws) ----
        v4f st[2];
#pragma unroll
        for (int mi = 0; mi < 2; mi++) {
            int ms = ws * 2 + mi;
            v8s aK = *(const v8s*)&Ks[ms * 16 + l16][lg * 8];
            v4f z = {0.f, 0.f, 0.f, 0.f};
            st[mi] = __builtin_amdgcn_mfma_f32_16x16x32_bf16(aK, bQ, z, 0, 0, 0);
        }
        // partial max over this wave's 32 m's (8 reg vals + lg-shuffles)
        float pm = -3.0e38f;
#pragma unroll
        for (int mi = 0; mi < 2; mi++)
#pragma unroll
            for (int r = 0; r < 4; r++) pm = fmaxf(pm, st[mi][r]);
        pm = fmaxf(pm, __shfl_xor(pm, 16));
        pm = fmaxf(pm, __shfl_xor(pm, 32));
        if (l < 16) pmax2[ws][q] = pm;
        __syncthreads();                         // B3: partial maxes visible

        float mold = mrow[q];
        float mnew = fmaxf(fmaxf(pmax2[0][q], pmax2[1][q]), mold);
        float al   = __expf(mold - mnew);
        if (ws == 0 && l < 16) alr[q] = al;
        float p[2][4];
        float psum = 0.f;
#pragma unroll
        for (int mi = 0; mi < 2; mi++)
#pragma unroll
            for (int r = 0; r < 4; r++) {
                p[mi][r] = __expf(st[mi][r] - mnew);
                psum += p[mi][r];
            }
        psum += __shfl_xor(psum, 16);
        psum += __shfl_xor(psum, 32);
        if (l < 16) psum2[ws][q] = psum;
#pragma unroll
        for (int mi = 0; mi < 2; mi++) {         // P^T -> Pt[q][m] bf16
            uint2 pk;
            pk.x = pack2bf(p[mi][0], p[mi][1]);
            pk.y = pack2bf(p[mi][2], p[mi][3]);
            *(uint2*)&Pt[q][32 * ws + 16 * mi + 4 * lg] = pk;
        }
        __syncthreads();                         // B4: P ready

        if (t < 64) {                            // l/m bookkeeping (overlaps PV)
            float mo = mrow[t];
            float mn = fmaxf(fmaxf(pmax2[0][t], pmax2[1][t]), mo);
            float a2 = __expf(mo - mn);
            lrow[t] = lrow[t] * a2 + psum2[0][t] + psum2[1][t];
            mrow[t] = mn;
        }

        // ---- PV: O^T[c][q] accumulate ----
        {
            float a0 = alr[l16], a1 = alr[16 + l16], a2v = alr[32 + l16], a3 = alr[48 + l16];
#pragma unroll
            for (int cs = 0; cs < 2; cs++)
#pragma unroll
                for (int r = 0; r < 4; r++) {
                    acc[cs][0][r] *= a0; acc[cs][1][r] *= a1;
                    acc[cs][2][r] *= a2v; acc[cs][3][r] *= a3;
                }
#pragma unroll
            for (int kc = 0; kc < 2; kc++) {
                v8s bP[4];
#pragma unroll
                for (int qq = 0; qq < 4; qq++)
                    bP[qq] = *(const v8s*)&Pt[qq * 16 + l16][kc * 32 + lg * 8];
#pragma unroll
                for (int cs = 0; cs < 2; cs++) {
                    v8s aV = *(const v8s*)&Vs[(2 * w + cs) * 16 + l16][kc * 32 + lg * 8];
#pragma unroll
                    for (int qq = 0; qq < 4; qq++)
                        acc[cs][qq] = __builtin_amdgcn_mfma_f32_16x16x32_bf16(
                            aV, bP[qq], acc[cs][qq], 0, 0, 0);
                }
            }
        }
    }
    __syncthreads();                             // final lrow update visible

    const float gm = gamma[0];
#pragma unroll
    for (int qq = 0; qq < 4; qq++) {
        float il = 1.0f / lrow[qq * 16 + l16];
        int   n  = q0 + qq * 16 + l16;
#pragma unroll
        for (int cs = 0; cs < 2; cs++)
#pragma unroll
            for (int r = 0; r < 4; r++) {
                int c = (2 * w + cs) * 16 + lg * 4 + r;
                size_t idx = ((size_t)b * C_ + c) * N_ + n;
                out[idx] = gm * (acc[cs][qq][r] * il) + x[idx];
            }
    }
}

extern "C" void kernel_launch(void* const* d_in, const int* in_sizes, int n_in,
                              void* d_out, int out_size, void* d_ws, size_t ws_size,
                              hipStream_t stream)
{
    const float* x  = (const float*)d_in[0];
    const float* Wb = (const float*)d_in[1];
    const float* bb = (const float*)d_in[2];
    const float* Wc = (const float*)d_in[3];
    const float* bc = (const float*)d_in[4];
    const float* Wd = (const float*)d_in[5];
    const float* bd = (const float*)d_in[6];
    const float* gm = (const float*)d_in[7];
    float* out = (float*)d_out;

    unsigned short* Qw = (unsigned short*)d_ws;            // B*N*32 bf16
    unsigned short* Kw = Qw + (size_t)B_ * N_ * 32;        // B*N*32 bf16
    unsigned short* Vw = Kw + (size_t)B_ * N_ * 32;        // B*C*N bf16
    unsigned short* Wcat = Vw + (size_t)B_ * C_ * N_;      // 320*256 bf16

    wcvt_kernel<<<dim3(80), 256, 0, stream>>>(Wb, Wc, Wd, Wcat);
    proj_mfma<<<dim3(N_ / 64, B_), 512, 0, stream>>>(x, Wcat, bb, bc, bd, Qw, Kw, Vw);
    attn_mfma<<<dim3(N_ / 64, B_), 512, 0, stream>>>(Qw, Kw, Vw, x, gm, out);
}